// Round 14
// baseline (520.805 us; speedup 1.0000x reference)
//
#include <hip/hip_runtime.h>
#include <hip/hip_bf16.h>

#define NT      8
#define TD      100
#define FEAT    172
#define DIN     272     // FEAT + TD
#define KPAD    288     // padded K, 9 * 32
#define NKS     9       // KPAD / 32
#define OUTD    128
#define BM      32      // rows per MFMA sub-tile (2 rowblocks of 16)
#define WIN     512     // edges per block (16 sub-tiles)
#define NST     (WIN / BM)
#define TWO_PI  6.283185307179586

typedef __bf16 bf16x8 __attribute__((ext_vector_type(8)));
typedef float  f32x4  __attribute__((ext_vector_type(4)));
typedef short  s16x8  __attribute__((ext_vector_type(8)));

__device__ __forceinline__ unsigned short f2bf(float f) {
    __hip_bfloat16 h = __float2bfloat16(f);        // 1-op HW convert (RNE)
    return __builtin_bit_cast(unsigned short, h);
}

// ---------------- dtype detection (int32 vs int64 edge_types) ----------------
__global__ void k_detect(const int* __restrict__ words, int* __restrict__ flag) {
    __shared__ int s_or;
    if (threadIdx.x == 0) s_or = 0;
    __syncthreads();
    int v  = words[2 * threadIdx.x + 1];
    int v2 = words[2 * (threadIdx.x + 256) + 1];
    if (v | v2) atomicOr(&s_or, 1);
    __syncthreads();
    if (threadIdx.x == 0) *flag = (s_or == 0) ? 1 : 0;   // 1 => int64
}

__device__ __forceinline__ int get_type(const int* __restrict__ p, int e, int is64) {
    return p[is64 ? (2 * e) : e] & 7;
}

// ---------------- table prep ----------------
__global__ void k_prep_tables(const float* __restrict__ b, const float* __restrict__ temb,
                              float* __restrict__ freq_base, float* __restrict__ bias) {
    int gid = blockIdx.x * blockDim.x + threadIdx.x;
    if (gid < TD)
        freq_base[gid] = (float)(pow(10.0, -(double)gid / 11.0) / TWO_PI);
    if (gid < NT * OUTD) bias[gid] = b[gid] + temb[gid];
}

// W[t][k][n] fp32 -> bf16 fragment order: bfrag[(((t*NKS+s)*8+nf)*64+lane)*8+i]
// lane: col = nf*16 + (lane&15), k = s*32 + (lane>>4)*8 + i   [HW-verified R3/R6]
__global__ void k_prep_bfrag(const float* __restrict__ W, unsigned short* __restrict__ bfrag) {
    int gid = blockIdx.x * blockDim.x + threadIdx.x;
    if (gid >= NT * NKS * 8 * 64) return;
    int lane = gid & 63;
    int rest = gid >> 6;
    int nf = rest & 7; rest >>= 3;
    int s = rest % NKS, t = rest / NKS;
    int n  = nf * 16 + (lane & 15);
    int kb = s * 32 + (lane >> 4) * 8;
    unsigned short v[8];
    #pragma unroll
    for (int i = 0; i < 8; ++i) {
        int k = kb + i;
        float x = (k < DIN) ? W[((size_t)t * DIN + k) * OUTD + n] : 0.0f;
        v[i] = f2bf(x);
    }
    unsigned short* dst = bfrag + (size_t)gid * 8;
    #pragma unroll
    for (int i = 0; i < 8; ++i) dst[i] = v[i];
}

// ---------------- A-fragment builders (per-lane, register-direct) ----------------
__device__ __forceinline__ s16x8 build_feat8(const float* __restrict__ rowp, int k0) {
    float4 fa = *(const float4*)(rowp + k0);
    float4 fb = *(const float4*)(rowp + k0 + 4);
    s16x8 v;
    v[0] = (short)f2bf(fa.x); v[1] = (short)f2bf(fa.y);
    v[2] = (short)f2bf(fa.z); v[3] = (short)f2bf(fa.w);
    v[4] = (short)f2bf(fb.x); v[5] = (short)f2bf(fb.y);
    v[6] = (short)f2bf(fb.z); v[7] = (short)f2bf(fb.w);
    return v;
}

__device__ __forceinline__ float cosrev(float tm, float fq) {
    float rev = tm * fq;
    float fr  = rev - floorf(rev);
    return __builtin_amdgcn_cosf(fr);      // cos(2*pi*fr)
}

__device__ __forceinline__ s16x8 build_cos8(float tm, const float* __restrict__ fql, int j0) {
    s16x8 v;
    #pragma unroll
    for (int i = 0; i < 8; ++i)
        v[i] = (short)f2bf(cosrev(tm, fql[j0 + i]));
    return v;
}

// k0 in {160,168,176,184}: per-element feat (k<172) or cos
__device__ __forceinline__ s16x8 build_mix(const float* __restrict__ rowp, float tm,
                                           const float* __restrict__ fql, int k0) {
    int ia = min(k0 >> 2, 41);      // clamped float4 indices (row has 43 float4s)
    float4 fa = ((const float4*)rowp)[ia];
    float4 fb = ((const float4*)rowp)[ia + 1];
    float fv[8] = {fa.x, fa.y, fa.z, fa.w, fb.x, fb.y, fb.z, fb.w};
    s16x8 v;
    #pragma unroll
    for (int i = 0; i < 8; ++i) {
        int k = k0 + i;
        int j = k - FEAT; j = j < 0 ? 0 : j;
        float fe = fv[(k - 4 * ia) & 7];
        float cv = cosrev(tm, fql[j]);
        v[i] = (short)f2bf(k < FEAT ? fe : cv);
    }
    return v;
}

// k0 = 256 + hq*8: cos for k<272, zero pad beyond
__device__ __forceinline__ s16x8 build_tail(float tm, const float* __restrict__ fql, int k0) {
    s16x8 v;
    #pragma unroll
    for (int i = 0; i < 8; ++i) {
        int k = k0 + i;
        int j = k - FEAT; j = j > (TD - 1) ? (TD - 1) : j;
        float cv = cosrev(tm, fql[j]);
        v[i] = (short)f2bf(k < DIN ? cv : 0.0f);
    }
    return v;
}

// ---------------- main kernel: barrier-free per-wave subtiles ----------------
// Window = 512 consecutive edges, counting-sorted in LDS (3 barriers).
// After the sort, each of the 4 waves independently processes subtiles
// {w, w+4, w+8, w+12}: builds its 32-row A-fragment set in registers
// (feat gather + cos, ONCE), then per type present: stream 72 B-loads +
// 144 MFMA, predicated coalesced stores. No barriers, no LDS A-tile.
__global__ __launch_bounds__(256, 3) void k_main(
    const float* __restrict__ feats, const float* __restrict__ ts,
    const int* __restrict__ types, const int* __restrict__ flag,
    float* __restrict__ out, const float* __restrict__ freq_base,
    const float* __restrict__ bias_tab, const unsigned short* __restrict__ bfrag,
    int E)
{
    __shared__ unsigned short pt[WIN];   // local_idx(9b) | type<<12 ; 0xFFFF invalid
    __shared__ float tsm[WIN];           // ts[e] * (1 + 0.1*t), by sorted slot
    __shared__ float freq_lds[TD];
    __shared__ int cnt[NT];
    __shared__ int seg[NT + 1];
    __shared__ int um[NST];              // per-sub-tile type union mask

    const int tid = threadIdx.x;
    const long base_e = (long)blockIdx.x * WIN;
    const int is64 = *flag;

    if (tid < NT)  cnt[tid] = 0;
    if (tid < NST) um[tid] = 0;
    if (tid < TD)  freq_lds[tid] = freq_base[tid];
    pt[tid] = 0xFFFF;        pt[tid + 256] = 0xFFFF;
    tsm[tid] = 0.0f;         tsm[tid + 256] = 0.0f;
    __syncthreads();

    // counting sort: 2 edges per thread
    int t0 = -1, t1 = -1; float f0 = 0.f, f1 = 0.f;
    {
        long e0 = base_e + tid, e1 = base_e + tid + 256;
        if (e0 < (long)E) { t0 = get_type(types, (int)e0, is64);
                            f0 = ts[e0] * (1.0f + 0.1f * (float)t0); atomicAdd(&cnt[t0], 1); }
        if (e1 < (long)E) { t1 = get_type(types, (int)e1, is64);
                            f1 = ts[e1] * (1.0f + 0.1f * (float)t1); atomicAdd(&cnt[t1], 1); }
    }
    __syncthreads();
    if (tid == 0) {
        int a = 0;
        #pragma unroll
        for (int t = 0; t < NT; ++t) { seg[t] = a; a += cnt[t]; cnt[t] = 0; }
        seg[NT] = a;
    }
    __syncthreads();
    if (t0 >= 0) {
        int r = seg[t0] + atomicAdd(&cnt[t0], 1);
        pt[r] = (unsigned short)(tid | (t0 << 12));
        tsm[r] = f0;
        atomicOr(&um[r >> 5], 1 << t0);
    }
    if (t1 >= 0) {
        int r = seg[t1] + atomicAdd(&cnt[t1], 1);
        pt[r] = (unsigned short)((tid + 256) | (t1 << 12));
        tsm[r] = f1;
        atomicOr(&um[r >> 5], 1 << t1);
    }
    __syncthreads();           // LAST barrier — waves independent from here

    const int w = tid >> 6, lane = tid & 63;
    const int hq = lane >> 4, l15 = lane & 15;
    const int hq8 = hq * 8;

    #pragma unroll 1
    for (int st = w; st < NST; st += 4) {
        const int rbase = st * BM;
        const int mask0 = um[st];
        if (!mask0) continue;

        // lane's A rows (r15 within each 16-row fragment)
        unsigned pa0 = pt[rbase + l15];
        unsigned pa1 = pt[rbase + 16 + l15];
        const float* row0 = feats + (base_e + (pa0 == 0xFFFFu ? 0 : (pa0 & 0x1FF))) * (long)FEAT;
        const float* row1 = feats + (base_e + (pa1 == 0xFFFFu ? 0 : (pa1 & 0x1FF))) * (long)FEAT;
        const float tm0 = tsm[rbase + l15];
        const float tm1 = tsm[rbase + 16 + l15];

        // row metadata for stores (C/D map: row = rb*16 + hq*4 + rg)
        unsigned pm0[4], pm1[4];
        #pragma unroll
        for (int rg = 0; rg < 4; ++rg) {
            pm0[rg] = pt[rbase + hq * 4 + rg];
            pm1[rg] = pt[rbase + 16 + hq * 4 + rg];
        }

        // ---- build full A-fragment set in registers (once per subtile)
        s16x8 a0[NKS], a1[NKS];
        #pragma unroll
        for (int s = 0; s < 5; ++s) {
            a0[s] = build_feat8(row0, s * 32 + hq8);
            a1[s] = build_feat8(row1, s * 32 + hq8);
        }
        a0[5] = build_mix(row0, tm0, freq_lds, 160 + hq8);
        a1[5] = build_mix(row1, tm1, freq_lds, 160 + hq8);
        #pragma unroll
        for (int s = 6; s < 8; ++s) {
            a0[s] = build_cos8(tm0, freq_lds, s * 32 + hq8 - FEAT);
            a1[s] = build_cos8(tm1, freq_lds, s * 32 + hq8 - FEAT);
        }
        a0[8] = build_tail(tm0, freq_lds, 256 + hq8);
        a1[8] = build_tail(tm1, freq_lds, 256 + hq8);

        // ---- per-type MFMA streams
        int mask = mask0;
        while (mask) {
            const int t = __ffs(mask) - 1; mask &= mask - 1;
            const s16x8* bp = (const s16x8*)bfrag + (size_t)t * (NKS * 8 * 64) + lane;
            f32x4 acc[8][2];
            #pragma unroll
            for (int nf = 0; nf < 8; ++nf) {
                acc[nf][0] = (f32x4){0.f, 0.f, 0.f, 0.f};
                acc[nf][1] = (f32x4){0.f, 0.f, 0.f, 0.f};
            }
            #pragma unroll 2
            for (int s = 0; s < NKS; ++s) {
                bf16x8 av0 = __builtin_bit_cast(bf16x8, a0[s]);
                bf16x8 av1 = __builtin_bit_cast(bf16x8, a1[s]);
                #pragma unroll
                for (int nf = 0; nf < 8; ++nf) {
                    bf16x8 bb = __builtin_bit_cast(bf16x8, bp[(s * 8 + nf) * 64]);
                    acc[nf][0] = __builtin_amdgcn_mfma_f32_16x16x32_bf16(av0, bb, acc[nf][0], 0, 0, 0);
                    acc[nf][1] = __builtin_amdgcn_mfma_f32_16x16x32_bf16(av1, bb, acc[nf][1], 0, 0, 0);
                }
            }
            #pragma unroll
            for (int nf = 0; nf < 8; ++nf) {
                const float bias = bias_tab[t * OUTD + nf * 16 + l15];
                #pragma unroll
                for (int rg = 0; rg < 4; ++rg) {
                    if ((int)(pm0[rg] >> 12) == t)
                        out[(size_t)(base_e + (pm0[rg] & 0x1FF)) * OUTD + nf * 16 + l15] = acc[nf][0][rg] + bias;
                    if ((int)(pm1[rg] >> 12) == t)
                        out[(size_t)(base_e + (pm1[rg] & 0x1FF)) * OUTD + nf * 16 + l15] = acc[nf][1][rg] + bias;
                }
            }
        }
    }
}

// ---------------- launch ----------------
extern "C" void kernel_launch(void* const* d_in, const int* in_sizes, int n_in,
                              void* d_out, int out_size, void* d_ws, size_t ws_size,
                              hipStream_t stream) {
    const float* feats = (const float*)d_in[0];
    const float* ts    = (const float*)d_in[1];
    const int*   types = (const int*)d_in[2];
    const float* W     = (const float*)d_in[3];
    const float* b     = (const float*)d_in[4];
    const float* temb  = (const float*)d_in[5];
    float* out = (float*)d_out;
    const int E = in_sizes[1];

    char* ws = (char*)d_ws;
    auto align256 = [](size_t x) { return (x + 255) & ~(size_t)255; };
    int* flag = (int*)(ws + 0);
    size_t o = 256;
    float* freq_base = (float*)(ws + o); o = align256(o + TD * 4);
    float* bias      = (float*)(ws + o); o = align256(o + NT * OUTD * 4);
    unsigned short* bfrag = (unsigned short*)(ws + o);
    o = align256(o + (size_t)NT * NKS * 8 * 64 * 8 * 2);
    if (ws_size < o) return;

    k_detect<<<1, 256, 0, stream>>>(types, flag);
    k_prep_tables<<<8, 256, 0, stream>>>(b, temb, freq_base, bias);
    k_prep_bfrag<<<(NT * NKS * 8 * 64 + 255) / 256, 256, 0, stream>>>(W, bfrag);

    int nblocks = (E + WIN - 1) / WIN;
    k_main<<<nblocks, 256, 0, stream>>>(feats, ts, types, flag, out,
                                        freq_base, bias, bfrag, E);
}

// Round 15
// 359.707 us; speedup vs baseline: 1.4479x; 1.4479x over previous
//
#include <hip/hip_runtime.h>
#include <hip/hip_bf16.h>

#define NT      8
#define TD      100
#define FEAT    172
#define DIN     272     // FEAT + TD
#define KPAD    288     // padded K, 9 * 32
#define NKS     9       // KPAD / 32
#define OUTD    128
#define BM      16      // rows per MFMA sub-tile (ONE rowblock)
#define WIN     512     // edges per block (32 sub-tiles)
#define NST     (WIN / BM)
#define TWO_PI  6.283185307179586

typedef __bf16 bf16x8 __attribute__((ext_vector_type(8)));
typedef float  f32x4  __attribute__((ext_vector_type(4)));
typedef short  s16x8  __attribute__((ext_vector_type(8)));

__device__ __forceinline__ unsigned short f2bf(float f) {
    __hip_bfloat16 h = __float2bfloat16(f);        // 1-op HW convert (RNE)
    return __builtin_bit_cast(unsigned short, h);
}

// ---------------- dtype detection (int32 vs int64 edge_types) ----------------
__global__ void k_detect(const int* __restrict__ words, int* __restrict__ flag) {
    __shared__ int s_or;
    if (threadIdx.x == 0) s_or = 0;
    __syncthreads();
    int v  = words[2 * threadIdx.x + 1];
    int v2 = words[2 * (threadIdx.x + 256) + 1];
    if (v | v2) atomicOr(&s_or, 1);
    __syncthreads();
    if (threadIdx.x == 0) *flag = (s_or == 0) ? 1 : 0;   // 1 => int64
}

__device__ __forceinline__ int get_type(const int* __restrict__ p, int e, int is64) {
    return p[is64 ? (2 * e) : e] & 7;
}

// ---------------- table prep ----------------
__global__ void k_prep_tables(const float* __restrict__ b, const float* __restrict__ temb,
                              float* __restrict__ freq_base, float* __restrict__ bias) {
    int gid = blockIdx.x * blockDim.x + threadIdx.x;
    if (gid < TD)
        freq_base[gid] = (float)(pow(10.0, -(double)gid / 11.0) / TWO_PI);
    if (gid < NT * OUTD) bias[gid] = b[gid] + temb[gid];
}

// W[t][k][n] fp32 -> bf16 fragment order: bfrag[(((t*NKS+s)*8+nf)*64+lane)*8+i]
// lane: col = nf*16 + (lane&15), k = s*32 + (lane>>4)*8 + i   [HW-verified R3/R6]
__global__ void k_prep_bfrag(const float* __restrict__ W, unsigned short* __restrict__ bfrag) {
    int gid = blockIdx.x * blockDim.x + threadIdx.x;
    if (gid >= NT * NKS * 8 * 64) return;
    int lane = gid & 63;
    int rest = gid >> 6;
    int nf = rest & 7; rest >>= 3;
    int s = rest % NKS, t = rest / NKS;
    int n  = nf * 16 + (lane & 15);
    int kb = s * 32 + (lane >> 4) * 8;
    unsigned short v[8];
    #pragma unroll
    for (int i = 0; i < 8; ++i) {
        int k = kb + i;
        float x = (k < DIN) ? W[((size_t)t * DIN + k) * OUTD + n] : 0.0f;
        v[i] = f2bf(x);
    }
    unsigned short* dst = bfrag + (size_t)gid * 8;
    #pragma unroll
    for (int i = 0; i < 8; ++i) dst[i] = v[i];
}

// ---------------- A-fragment builders (per-lane, register-direct) ----------------
__device__ __forceinline__ s16x8 build_feat8(const float* __restrict__ rowp, int k0) {
    float4 fa = *(const float4*)(rowp + k0);
    float4 fb = *(const float4*)(rowp + k0 + 4);
    s16x8 v;
    v[0] = (short)f2bf(fa.x); v[1] = (short)f2bf(fa.y);
    v[2] = (short)f2bf(fa.z); v[3] = (short)f2bf(fa.w);
    v[4] = (short)f2bf(fb.x); v[5] = (short)f2bf(fb.y);
    v[6] = (short)f2bf(fb.z); v[7] = (short)f2bf(fb.w);
    return v;
}

__device__ __forceinline__ float cosrev(float tm, float fq) {
    float rev = tm * fq;
    float fr  = rev - floorf(rev);
    return __builtin_amdgcn_cosf(fr);      // cos(2*pi*fr)
}

__device__ __forceinline__ s16x8 build_cos8(float tm, const float* __restrict__ fql, int j0) {
    s16x8 v;
    #pragma unroll
    for (int i = 0; i < 8; ++i)
        v[i] = (short)f2bf(cosrev(tm, fql[j0 + i]));
    return v;
}

// k0 in {160,168,176,184}: per-element feat (k<172) or cos
__device__ __forceinline__ s16x8 build_mix(const float* __restrict__ rowp, float tm,
                                           const float* __restrict__ fql, int k0) {
    int ia = min(k0 >> 2, 41);      // clamped float4 indices (row has 43 float4s)
    float4 fa = ((const float4*)rowp)[ia];
    float4 fb = ((const float4*)rowp)[ia + 1];
    float fv[8] = {fa.x, fa.y, fa.z, fa.w, fb.x, fb.y, fb.z, fb.w};
    s16x8 v;
    #pragma unroll
    for (int i = 0; i < 8; ++i) {
        int k = k0 + i;
        int j = k - FEAT; j = j < 0 ? 0 : j;
        float fe = fv[(k - 4 * ia) & 7];
        float cv = cosrev(tm, fql[j]);
        v[i] = (short)f2bf(k < FEAT ? fe : cv);
    }
    return v;
}

// k0 = 256 + hq*8: cos for k<272, zero pad beyond
__device__ __forceinline__ s16x8 build_tail(float tm, const float* __restrict__ fql, int k0) {
    s16x8 v;
    #pragma unroll
    for (int i = 0; i < 8; ++i) {
        int k = k0 + i;
        int j = k - FEAT; j = j > (TD - 1) ? (TD - 1) : j;
        float cv = cosrev(tm, fql[j]);
        v[i] = (short)f2bf(k < DIN ? cv : 0.0f);
    }
    return v;
}

// ---------------- main kernel: barrier-free per-wave 16-row subtiles ----------------
// Window = 512 consecutive edges, counting-sorted in LDS (3 barriers).
// After the sort each wave independently owns subtiles {w, w+4, ...}:
// A built ONCE into 36 VGPRs (all loops fully unrolled — static indexing only),
// then per type present: 72 B-loads (L2-hot) + 72 MFMA + predicated stores.
__global__ __launch_bounds__(256, 3) void k_main(
    const float* __restrict__ feats, const float* __restrict__ ts,
    const int* __restrict__ types, const int* __restrict__ flag,
    float* __restrict__ out, const float* __restrict__ freq_base,
    const float* __restrict__ bias_tab, const unsigned short* __restrict__ bfrag,
    int E)
{
    __shared__ unsigned short pt[WIN];   // local_idx(9b) | type<<12 ; 0xFFFF invalid
    __shared__ float tsm[WIN];           // ts[e] * (1 + 0.1*t), by sorted slot
    __shared__ float freq_lds[TD];
    __shared__ int cnt[NT];
    __shared__ int seg[NT + 1];
    __shared__ int um[NST];              // per-16-row-sub-tile type union mask

    const int tid = threadIdx.x;
    const long base_e = (long)blockIdx.x * WIN;
    const int is64 = *flag;

    if (tid < NT)  cnt[tid] = 0;
    if (tid < NST) um[tid] = 0;
    if (tid < TD)  freq_lds[tid] = freq_base[tid];
    pt[tid] = 0xFFFF;        pt[tid + 256] = 0xFFFF;
    tsm[tid] = 0.0f;         tsm[tid + 256] = 0.0f;
    __syncthreads();

    // counting sort: 2 edges per thread
    int t0 = -1, t1 = -1; float f0 = 0.f, f1 = 0.f;
    {
        long e0 = base_e + tid, e1 = base_e + tid + 256;
        if (e0 < (long)E) { t0 = get_type(types, (int)e0, is64);
                            f0 = ts[e0] * (1.0f + 0.1f * (float)t0); atomicAdd(&cnt[t0], 1); }
        if (e1 < (long)E) { t1 = get_type(types, (int)e1, is64);
                            f1 = ts[e1] * (1.0f + 0.1f * (float)t1); atomicAdd(&cnt[t1], 1); }
    }
    __syncthreads();
    if (tid == 0) {
        int a = 0;
        #pragma unroll
        for (int t = 0; t < NT; ++t) { seg[t] = a; a += cnt[t]; cnt[t] = 0; }
        seg[NT] = a;
    }
    __syncthreads();
    if (t0 >= 0) {
        int r = seg[t0] + atomicAdd(&cnt[t0], 1);
        pt[r] = (unsigned short)(tid | (t0 << 12));
        tsm[r] = f0;
        atomicOr(&um[r >> 4], 1 << t0);
    }
    if (t1 >= 0) {
        int r = seg[t1] + atomicAdd(&cnt[t1], 1);
        pt[r] = (unsigned short)((tid + 256) | (t1 << 12));
        tsm[r] = f1;
        atomicOr(&um[r >> 4], 1 << t1);
    }
    __syncthreads();           // LAST barrier — waves independent from here

    const int w = tid >> 6, lane = tid & 63;
    const int hq = lane >> 4, l15 = lane & 15;
    const int hq8 = hq * 8;

    #pragma unroll 1
    for (int st = w; st < NST; st += 4) {
        const int rbase = st * BM;
        const int mask0 = um[st];
        if (!mask0) continue;

        // lane's A row (row = l15 within the 16-row fragment)
        unsigned pa = pt[rbase + l15];
        const float* row = feats + (base_e + (pa == 0xFFFFu ? 0 : (pa & 0x1FF))) * (long)FEAT;
        const float tm = tsm[rbase + l15];

        // row metadata for stores (C/D map: row = hq*4 + rg, m89-verified)
        unsigned pm[4];
        #pragma unroll
        for (int rg = 0; rg < 4; ++rg) pm[rg] = pt[rbase + hq * 4 + rg];

        // ---- build A fragments in registers (once; all static indexing)
        s16x8 a[NKS];
        a[0] = build_feat8(row, 0 * 32 + hq8);
        a[1] = build_feat8(row, 1 * 32 + hq8);
        a[2] = build_feat8(row, 2 * 32 + hq8);
        a[3] = build_feat8(row, 3 * 32 + hq8);
        a[4] = build_feat8(row, 4 * 32 + hq8);
        a[5] = build_mix(row, tm, freq_lds, 160 + hq8);
        a[6] = build_cos8(tm, freq_lds, 6 * 32 + hq8 - FEAT);
        a[7] = build_cos8(tm, freq_lds, 7 * 32 + hq8 - FEAT);
        a[8] = build_tail(tm, freq_lds, 256 + hq8);

        // ---- per-type MFMA streams (fully unrolled: static acc/a indexing)
        int mask = mask0;
        while (mask) {
            const int t = __ffs(mask) - 1; mask &= mask - 1;
            const s16x8* bp = (const s16x8*)bfrag + (size_t)t * (NKS * 8 * 64) + lane;
            f32x4 acc[8];
            #pragma unroll
            for (int nf = 0; nf < 8; ++nf) acc[nf] = (f32x4){0.f, 0.f, 0.f, 0.f};
            #pragma unroll
            for (int s = 0; s < NKS; ++s) {
                bf16x8 av = __builtin_bit_cast(bf16x8, a[s]);
                #pragma unroll
                for (int nf = 0; nf < 8; ++nf) {
                    bf16x8 bb = __builtin_bit_cast(bf16x8, bp[(s * 8 + nf) * 64]);
                    acc[nf] = __builtin_amdgcn_mfma_f32_16x16x32_bf16(av, bb, acc[nf], 0, 0, 0);
                }
            }
            #pragma unroll
            for (int nf = 0; nf < 8; ++nf) {
                const float bias = bias_tab[t * OUTD + nf * 16 + l15];
                #pragma unroll
                for (int rg = 0; rg < 4; ++rg)
                    if ((int)(pm[rg] >> 12) == t)
                        out[(size_t)(base_e + (pm[rg] & 0x1FF)) * OUTD + nf * 16 + l15]
                            = acc[nf][rg] + bias;
            }
        }
    }
}

// ---------------- launch ----------------
extern "C" void kernel_launch(void* const* d_in, const int* in_sizes, int n_in,
                              void* d_out, int out_size, void* d_ws, size_t ws_size,
                              hipStream_t stream) {
    const float* feats = (const float*)d_in[0];
    const float* ts    = (const float*)d_in[1];
    const int*   types = (const int*)d_in[2];
    const float* W     = (const float*)d_in[3];
    const float* b     = (const float*)d_in[4];
    const float* temb  = (const float*)d_in[5];
    float* out = (float*)d_out;
    const int E = in_sizes[1];

    char* ws = (char*)d_ws;
    auto align256 = [](size_t x) { return (x + 255) & ~(size_t)255; };
    int* flag = (int*)(ws + 0);
    size_t o = 256;
    float* freq_base = (float*)(ws + o); o = align256(o + TD * 4);
    float* bias      = (float*)(ws + o); o = align256(o + NT * OUTD * 4);
    unsigned short* bfrag = (unsigned short*)(ws + o);
    o = align256(o + (size_t)NT * NKS * 8 * 64 * 8 * 2);
    if (ws_size < o) return;

    k_detect<<<1, 256, 0, stream>>>(types, flag);
    k_prep_tables<<<8, 256, 0, stream>>>(b, temb, freq_base, bias);
    k_prep_bfrag<<<(NT * NKS * 8 * 64 + 255) / 256, 256, 0, stream>>>(W, bfrag);

    int nblocks = (E + WIN - 1) / WIN;
    k_main<<<nblocks, 256, 0, stream>>>(feats, ts, types, flag, out,
                                        freq_base, bias, bfrag, E);
}